// Round 5
// baseline (596.219 us; speedup 1.0000x reference)
//
#include <hip/hip_runtime.h>

#define SG 128
#define C 32
#define NPB 250000
#define BATCH 2
#define M (BATCH * NPB)
#define NK 27

typedef __attribute__((ext_vector_type(4))) float f32x4;
typedef __attribute__((ext_vector_type(8))) short bf16x8;

union frag_u { unsigned u[4]; bf16x8 v; };

// ---------------- scatter: fill voxel grid with point indices ----------------
__global__ void scatter_kernel(const int* __restrict__ coords, int* __restrict__ grid) {
    int p = blockIdx.x * blockDim.x + threadIdx.x;
    if (p >= M) return;
    int x = coords[3 * p + 0];
    int y = coords[3 * p + 1];
    int z = coords[3 * p + 2];
    int b = (p >= NPB) ? 1 : 0;
    grid[((b * SG + x) * SG + y) * SG + z] = p;
}

// ---------------- build neighbor table nb[k][p] ----------------
__global__ void build_nb_kernel(const int* __restrict__ coords,
                                const int* __restrict__ grid,
                                int* __restrict__ nb) {
    int p = blockIdx.x * blockDim.x + threadIdx.x;
    if (p >= M) return;
    int x = coords[3 * p + 0];
    int y = coords[3 * p + 1];
    int z = coords[3 * p + 2];
    int base = (p >= NPB) ? SG * SG * SG : 0;
#pragma unroll
    for (int k = 0; k < NK; k++) {
        int nx = x + k / 9 - 1;
        int ny = y + (k / 3) % 3 - 1;
        int nz = z + (k % 3) - 1;
        int idx = -1;
        if ((unsigned)nx < SG && (unsigned)ny < SG && (unsigned)nz < SG)
            idx = grid[base + (nx * SG + ny) * SG + nz];
        nb[k * M + p] = idx;
    }
}

// ---------------- pack W into MFMA B-fragment layout, split bf16 hi/lo -------
// B-frag (16x16x32): lane l holds B[ci = 8*(l>>4)+j][co = ct*16 + (l&15)].
// wpk[tap][slot = ct*2+var][lane][j], per-tap stride 2048 ushorts.
__global__ void prep_w_kernel(const float* __restrict__ W, unsigned short* __restrict__ wpk) {
    int id = blockIdx.x * blockDim.x + threadIdx.x;
    if (id >= NK * 2 * 64) return;
    int l = id & 63, ct = (id >> 6) & 1, k = id >> 7;
    int lrow = l & 15, kg = l >> 4;
    unsigned hw[4], lw[4];
#pragma unroll
    for (int jp = 0; jp < 4; jp++) {
        float v0 = W[k * 1024 + (kg * 8 + 2 * jp + 0) * 32 + ct * 16 + lrow];
        float v1 = W[k * 1024 + (kg * 8 + 2 * jp + 1) * 32 + ct * 16 + lrow];
        unsigned u0 = __float_as_uint(v0), u1 = __float_as_uint(v1);
        hw[jp] = (u0 >> 16) | (u1 & 0xFFFF0000u);
        float h0 = __uint_as_float(u0 & 0xFFFF0000u);
        float h1 = __uint_as_float(u1 & 0xFFFF0000u);
        lw[jp] = (__float_as_uint(v0 - h0) >> 16) | (__float_as_uint(v1 - h1) & 0xFFFF0000u);
    }
    unsigned* dh = (unsigned*)(wpk + k * 2048 + ((ct * 2 + 0) * 64 + l) * 8);
    unsigned* dl = (unsigned*)(wpk + k * 2048 + ((ct * 2 + 1) * 64 + l) * 8);
#pragma unroll
    for (int i = 0; i < 4; i++) { dh[i] = hw[i]; dl[i] = lw[i]; }
}

__device__ __forceinline__ void split1(float v, unsigned short& h, unsigned short& lo) {
    unsigned u = __float_as_uint(v);
    h = (unsigned short)(u >> 16);
    float hf = __uint_as_float(u & 0xFFFF0000u);
    lo = (unsigned short)(__float_as_uint(v - hf) >> 16);
}

// ---------------- split input features f32 -> packed hi|lo bf16 rows ---------
__global__ void split_in_kernel(const float* __restrict__ f, unsigned short* __restrict__ fpk) {
    int id = blockIdx.x * blockDim.x + threadIdx.x;
    if (id >= M * 8) return;
    int p = id >> 3, c4 = id & 7;
    f32x4 v = *(const f32x4*)&f[p * 32 + c4 * 4];
    ushort4 h, lo;
    split1(v[0], h.x, lo.x);
    split1(v[1], h.y, lo.y);
    split1(v[2], h.z, lo.z);
    split1(v[3], h.w, lo.w);
    *(ushort4*)&fpk[p * 64 + c4 * 4] = h;
    *(ushort4*)&fpk[p * 64 + 32 + c4 * 4] = lo;
}

// ---------------- conv: wave = 64 output points, dense 27 taps, MFMA ---------
// A-frag: lane l holds A[row = l&15][ci = 8*(l>>4)+j]; D: row=4*(l>>4)+j, col=l&15.
// fpk rows: [hi x32 | lo x32] bf16 (128 B). Split math identical to round 4.
template <bool RELU, bool LAST>
__global__ __launch_bounds__(256) void conv_mfma(
    const unsigned short* __restrict__ fpk,  // [M][64] packed hi|lo
    const int* __restrict__ nb,              // [NK][M]
    const unsigned short* __restrict__ wpk,  // packed B-frags
    unsigned short* __restrict__ opk,        // [M][64] if !LAST
    float* __restrict__ of32)                // [M][32] if LAST
{
    const int t = threadIdx.x;
    const int l = t & 63;
    const int wbase = (blockIdx.x * 4 + (t >> 6)) * 64;
    if (wbase >= M) return;
    const int lrow = l & 15, kg = l >> 4, ci0 = kg * 8;

    f32x4 acc[4][2];
#pragma unroll
    for (int rt = 0; rt < 4; rt++)
#pragma unroll
        for (int ct = 0; ct < 2; ct++) acc[rt][ct] = (f32x4){0.f, 0.f, 0.f, 0.f};

    for (int k = 0; k < NK; k++) {
        const unsigned short* wb = wpk + (k << 11);
        frag_u bh0, bl0, bh1, bl1;
        bh0.v = *(const bf16x8*)(wb + ((0 * 64 + l) << 3));
        bl0.v = *(const bf16x8*)(wb + ((1 * 64 + l) << 3));
        bh1.v = *(const bf16x8*)(wb + ((2 * 64 + l) << 3));
        bl1.v = *(const bf16x8*)(wb + ((3 * 64 + l) << 3));

        const int* nbk = nb + k * M;
#pragma unroll
        for (int rt = 0; rt < 4; rt++) {
            int row = wbase + rt * 16 + lrow;
            int idx = (row < M) ? nbk[row] : -1;
            frag_u ah, al;
            if (idx >= 0) {
                const unsigned short* src = fpk + idx * 64 + ci0;
                ah.v = *(const bf16x8*)(src);
                al.v = *(const bf16x8*)(src + 32);
            } else {
                ah.u[0] = ah.u[1] = ah.u[2] = ah.u[3] = 0;
                al.u[0] = al.u[1] = al.u[2] = al.u[3] = 0;
            }
            acc[rt][0] = __builtin_amdgcn_mfma_f32_16x16x32_bf16(ah.v, bh0.v, acc[rt][0], 0, 0, 0);
            acc[rt][1] = __builtin_amdgcn_mfma_f32_16x16x32_bf16(ah.v, bh1.v, acc[rt][1], 0, 0, 0);
            acc[rt][0] = __builtin_amdgcn_mfma_f32_16x16x32_bf16(ah.v, bl0.v, acc[rt][0], 0, 0, 0);
            acc[rt][1] = __builtin_amdgcn_mfma_f32_16x16x32_bf16(ah.v, bl1.v, acc[rt][1], 0, 0, 0);
            acc[rt][0] = __builtin_amdgcn_mfma_f32_16x16x32_bf16(al.v, bh0.v, acc[rt][0], 0, 0, 0);
            acc[rt][1] = __builtin_amdgcn_mfma_f32_16x16x32_bf16(al.v, bh1.v, acc[rt][1], 0, 0, 0);
        }
    }

    // epilogue: relu, then f32 store (last layer) or hi/lo bf16 packed store
#pragma unroll
    for (int rt = 0; rt < 4; rt++) {
        int rbase = wbase + rt * 16 + 4 * kg;
#pragma unroll
        for (int ct = 0; ct < 2; ct++) {
            int col = ct * 16 + lrow;
#pragma unroll
            for (int j = 0; j < 4; j++) {
                int row = rbase + j;
                if (row < M) {
                    float v = acc[rt][ct][j];
                    if (RELU) v = fmaxf(v, 0.f);
                    if (LAST) {
                        of32[row * 32 + col] = v;
                    } else {
                        unsigned short h, lo;
                        split1(v, h, lo);
                        opk[row * 64 + col] = h;
                        opk[row * 64 + 32 + col] = lo;
                    }
                }
            }
        }
    }
}

extern "C" void kernel_launch(void* const* d_in, const int* in_sizes, int n_in,
                              void* d_out, int out_size, void* d_ws, size_t ws_size,
                              hipStream_t stream) {
    const float* features    = (const float*)d_in[0];
    const int*   coordinates = (const int*)d_in[1];
    const float* W1 = (const float*)d_in[4];
    const float* W2 = (const float*)d_in[5];
    const float* W3 = (const float*)d_in[6];

    char* ws = (char*)d_ws;
    const size_t GRID_BYTES = (size_t)BATCH * SG * SG * SG * 4;   // 16.78 MB
    const size_t NB_BYTES   = (size_t)NK * M * 4;                 // 54.0 MB
    const size_t WPK_BYTES  = (size_t)NK * 2048 * 2;              // 110,592 B

    int* grid = (int*)ws;
    int* nbl  = (int*)(ws + GRID_BYTES);
    unsigned short* wpk1 = (unsigned short*)(ws + GRID_BYTES + NB_BYTES);
    unsigned short* wpk2 = (unsigned short*)(ws + GRID_BYTES + NB_BYTES + WPK_BYTES);
    unsigned short* wpk3 = (unsigned short*)(ws + GRID_BYTES + NB_BYTES + 2 * WPK_BYTES);
    unsigned short* fpk_a = (unsigned short*)(ws + GRID_BYTES + NB_BYTES + 3 * WPK_BYTES); // 64 MB
    unsigned short* fpk_b = (unsigned short*)d_out;  // 64 MB, overwritten by final f32 out
    float* out = (float*)d_out;

    hipMemsetAsync(grid, 0xFF, GRID_BYTES, stream);
    scatter_kernel<<<(M + 255) / 256, 256, 0, stream>>>(coordinates, grid);
    build_nb_kernel<<<(M + 255) / 256, 256, 0, stream>>>(coordinates, grid, nbl);

    const int PW = NK * 2 * 64;
    prep_w_kernel<<<(PW + 255) / 256, 256, 0, stream>>>(W1, wpk1);
    prep_w_kernel<<<(PW + 255) / 256, 256, 0, stream>>>(W2, wpk2);
    prep_w_kernel<<<(PW + 255) / 256, 256, 0, stream>>>(W3, wpk3);

    split_in_kernel<<<(M * 8 + 255) / 256, 256, 0, stream>>>(features, fpk_a);

    const int nwave = (M + 63) / 64;
    const int nblk  = (nwave + 3) / 4;
    conv_mfma<true,  false><<<nblk, 256, 0, stream>>>(fpk_a, nbl, wpk1, fpk_b, nullptr);
    conv_mfma<true,  false><<<nblk, 256, 0, stream>>>(fpk_b, nbl, wpk2, fpk_a, nullptr);
    conv_mfma<false, true ><<<nblk, 256, 0, stream>>>(fpk_a, nbl, wpk3, nullptr, out);
}

// Round 6
// 487.386 us; speedup vs baseline: 1.2233x; 1.2233x over previous
//
#include <hip/hip_runtime.h>

#define SG 128
#define C 32
#define NPB 250000
#define BATCH 2
#define M (BATCH * NPB)
#define MP 500032            // M padded to multiple of 64
#define NK 27

typedef __attribute__((ext_vector_type(4))) float f32x4;
typedef __attribute__((ext_vector_type(8))) short bf16x8;

union frag_u { unsigned u[4]; bf16x8 v; };
struct FragSet { frag_u ah[4], al[4], bh0, bl0, bh1, bl1; };

// ---------------- scatter: fill voxel grid with point indices ----------------
__global__ void scatter_kernel(const int* __restrict__ coords, int* __restrict__ grid) {
    int p = blockIdx.x * blockDim.x + threadIdx.x;
    if (p >= M) return;
    int x = coords[3 * p + 0];
    int y = coords[3 * p + 1];
    int z = coords[3 * p + 2];
    int b = (p >= NPB) ? 1 : 0;
    grid[((b * SG + x) * SG + y) * SG + z] = p;
}

// ---------------- build neighbor table nb[k][MP], pad rows = -1 --------------
__global__ void build_nb_kernel(const int* __restrict__ coords,
                                const int* __restrict__ grid,
                                int* __restrict__ nb) {
    int p = blockIdx.x * blockDim.x + threadIdx.x;
    if (p >= MP) return;
    if (p >= M) {
#pragma unroll
        for (int k = 0; k < NK; k++) nb[k * MP + p] = -1;
        return;
    }
    int x = coords[3 * p + 0];
    int y = coords[3 * p + 1];
    int z = coords[3 * p + 2];
    int base = (p >= NPB) ? SG * SG * SG : 0;
#pragma unroll
    for (int k = 0; k < NK; k++) {
        int nx = x + k / 9 - 1;
        int ny = y + (k / 3) % 3 - 1;
        int nz = z + (k % 3) - 1;
        int idx = -1;
        if ((unsigned)nx < SG && (unsigned)ny < SG && (unsigned)nz < SG)
            idx = grid[base + (nx * SG + ny) * SG + nz];
        nb[k * MP + p] = idx;
    }
}

// ---------------- pack W into MFMA B-fragment layout, split bf16 hi/lo -------
// B-frag (16x16x32): lane l holds B[ci = 8*(l>>4)+j][co = ct*16 + (l&15)].
__global__ void prep_w_kernel(const float* __restrict__ W, unsigned short* __restrict__ wpk) {
    int id = blockIdx.x * blockDim.x + threadIdx.x;
    if (id >= NK * 2 * 64) return;
    int l = id & 63, ct = (id >> 6) & 1, k = id >> 7;
    int lrow = l & 15, kg = l >> 4;
    unsigned hw[4], lw[4];
#pragma unroll
    for (int jp = 0; jp < 4; jp++) {
        float v0 = W[k * 1024 + (kg * 8 + 2 * jp + 0) * 32 + ct * 16 + lrow];
        float v1 = W[k * 1024 + (kg * 8 + 2 * jp + 1) * 32 + ct * 16 + lrow];
        unsigned u0 = __float_as_uint(v0), u1 = __float_as_uint(v1);
        hw[jp] = (u0 >> 16) | (u1 & 0xFFFF0000u);
        float h0 = __uint_as_float(u0 & 0xFFFF0000u);
        float h1 = __uint_as_float(u1 & 0xFFFF0000u);
        lw[jp] = (__float_as_uint(v0 - h0) >> 16) | (__float_as_uint(v1 - h1) & 0xFFFF0000u);
    }
    unsigned* dh = (unsigned*)(wpk + k * 2048 + ((ct * 2 + 0) * 64 + l) * 8);
    unsigned* dl = (unsigned*)(wpk + k * 2048 + ((ct * 2 + 1) * 64 + l) * 8);
#pragma unroll
    for (int i = 0; i < 4; i++) { dh[i] = hw[i]; dl[i] = lw[i]; }
}

__device__ __forceinline__ void split1(float v, unsigned short& h, unsigned short& lo) {
    unsigned u = __float_as_uint(v);
    h = (unsigned short)(u >> 16);
    float hf = __uint_as_float(u & 0xFFFF0000u);
    lo = (unsigned short)(__float_as_uint(v - hf) >> 16);
}

// ---------------- split input features f32 -> packed hi|lo bf16 rows ---------
__global__ void split_in_kernel(const float* __restrict__ f, unsigned short* __restrict__ fpk) {
    int id = blockIdx.x * blockDim.x + threadIdx.x;
    if (id >= M * 8) return;
    int p = id >> 3, c4 = id & 7;
    f32x4 v = *(const f32x4*)&f[p * 32 + c4 * 4];
    ushort4 h, lo;
    split1(v[0], h.x, lo.x);
    split1(v[1], h.y, lo.y);
    split1(v[2], h.z, lo.z);
    split1(v[3], h.w, lo.w);
    *(ushort4*)&fpk[p * 64 + c4 * 4] = h;
    *(ushort4*)&fpk[p * 64 + 32 + c4 * 4] = lo;
}

// ---------------- pipelined conv helpers ----------------
__device__ __forceinline__ void load_nb4(int* nbv, const int* __restrict__ nb,
                                         int k, int rowb) {
    const int* nbk = nb + k * MP + rowb;
    nbv[0] = nbk[0];
    nbv[1] = nbk[16];
    nbv[2] = nbk[32];
    nbv[3] = nbk[48];
}

__device__ __forceinline__ void load_AW(FragSet& s, const int* nbv,
                                        const unsigned short* __restrict__ fpk,
                                        const unsigned short* __restrict__ zrow,
                                        const unsigned short* __restrict__ wpk,
                                        int k, int l, int ci0) {
    const unsigned short* wb = wpk + (k << 11);
    s.bh0.v = *(const bf16x8*)(wb + ((0 * 64 + l) << 3));
    s.bl0.v = *(const bf16x8*)(wb + ((1 * 64 + l) << 3));
    s.bh1.v = *(const bf16x8*)(wb + ((2 * 64 + l) << 3));
    s.bl1.v = *(const bf16x8*)(wb + ((3 * 64 + l) << 3));
#pragma unroll
    for (int rt = 0; rt < 4; rt++) {
        int idx = nbv[rt];
        const unsigned short* src = (idx >= 0) ? (fpk + (size_t)idx * 64) : zrow;
        s.ah[rt].v = *(const bf16x8*)(src + ci0);
        s.al[rt].v = *(const bf16x8*)(src + ci0 + 32);
    }
}

__device__ __forceinline__ void do_mfma(const FragSet& s, f32x4 (&acc)[4][2]) {
#pragma unroll
    for (int rt = 0; rt < 4; rt++) {
        acc[rt][0] = __builtin_amdgcn_mfma_f32_16x16x32_bf16(s.ah[rt].v, s.bh0.v, acc[rt][0], 0, 0, 0);
        acc[rt][1] = __builtin_amdgcn_mfma_f32_16x16x32_bf16(s.ah[rt].v, s.bh1.v, acc[rt][1], 0, 0, 0);
        acc[rt][0] = __builtin_amdgcn_mfma_f32_16x16x32_bf16(s.ah[rt].v, s.bl0.v, acc[rt][0], 0, 0, 0);
        acc[rt][1] = __builtin_amdgcn_mfma_f32_16x16x32_bf16(s.ah[rt].v, s.bl1.v, acc[rt][1], 0, 0, 0);
        acc[rt][0] = __builtin_amdgcn_mfma_f32_16x16x32_bf16(s.al[rt].v, s.bh0.v, acc[rt][0], 0, 0, 0);
        acc[rt][1] = __builtin_amdgcn_mfma_f32_16x16x32_bf16(s.al[rt].v, s.bh1.v, acc[rt][1], 0, 0, 0);
    }
}

// ---------------- conv: wave = 64 output points, 2-deep pipelined ------------
// A-frag: lane l holds A[row = l&15][ci = 8*(l>>4)+j]; D: row=4*(l>>4)+j, col=l&15.
template <bool RELU, bool LAST>
__global__ __launch_bounds__(256) void conv_mfma(
    const unsigned short* __restrict__ fpk,  // [M][64] packed hi|lo
    const int* __restrict__ nb,              // [28][MP] (row 27 = prefetch pad)
    const unsigned short* __restrict__ wpk,  // packed B-frags
    const unsigned short* __restrict__ zrow, // 128 B of zeros
    unsigned short* __restrict__ opk,        // [M][64] if !LAST
    float* __restrict__ of32)                // [M][32] if LAST
{
    const int t = threadIdx.x;
    const int l = t & 63;
    const int wbase = (blockIdx.x * 4 + (t >> 6)) * 64;
    if (wbase >= MP) return;
    const int lrow = l & 15, kg = l >> 4, ci0 = kg * 8;
    const int rowb = wbase + lrow;

    f32x4 acc[4][2];
#pragma unroll
    for (int rt = 0; rt < 4; rt++)
#pragma unroll
        for (int ct = 0; ct < 2; ct++) acc[rt][ct] = (f32x4){0.f, 0.f, 0.f, 0.f};

    int nbv0[4], nbv1[4];
    FragSet A, B;

    load_nb4(nbv0, nb, 0, rowb);
    load_nb4(nbv1, nb, 1, rowb);
    load_AW(A, nbv0, fpk, zrow, wpk, 0, l, ci0);

#pragma unroll 1
    for (int k = 0; k < 25; k += 2) {
        load_nb4(nbv0, nb, k + 2, rowb);              // indices 2 taps ahead
        load_AW(B, nbv1, fpk, zrow, wpk, k + 1, l, ci0);
        do_mfma(A, acc);                              // tap k (loads issued last iter)
        load_nb4(nbv1, nb, k + 3, rowb);              // k+3 <= 27 (pad row)
        load_AW(A, nbv0, fpk, zrow, wpk, k + 2, l, ci0);
        do_mfma(B, acc);                              // tap k+1
    }
    do_mfma(A, acc);                                  // tap 26

    // epilogue: relu, then f32 store (last layer) or hi/lo bf16 packed store
#pragma unroll
    for (int rt = 0; rt < 4; rt++) {
        int rbase = wbase + rt * 16 + 4 * kg;
#pragma unroll
        for (int ct = 0; ct < 2; ct++) {
            int col = ct * 16 + lrow;
#pragma unroll
            for (int j = 0; j < 4; j++) {
                int row = rbase + j;
                if (row < M) {
                    float v = acc[rt][ct][j];
                    if (RELU) v = fmaxf(v, 0.f);
                    if (LAST) {
                        of32[row * 32 + col] = v;
                    } else {
                        unsigned short h, lo;
                        split1(v, h, lo);
                        opk[row * 64 + col] = h;
                        opk[row * 64 + 32 + col] = lo;
                    }
                }
            }
        }
    }
}

extern "C" void kernel_launch(void* const* d_in, const int* in_sizes, int n_in,
                              void* d_out, int out_size, void* d_ws, size_t ws_size,
                              hipStream_t stream) {
    const float* features    = (const float*)d_in[0];
    const int*   coordinates = (const int*)d_in[1];
    const float* W1 = (const float*)d_in[4];
    const float* W2 = (const float*)d_in[5];
    const float* W3 = (const float*)d_in[6];

    char* ws = (char*)d_ws;
    const size_t GRID_BYTES = (size_t)BATCH * SG * SG * SG * 4;   // 16.78 MB
    const size_t NB_BYTES   = (size_t)28 * MP * 4;                // 56.0 MB (28 tap rows)
    const size_t WPK_BYTES  = (size_t)NK * 2048 * 2;              // 110,592 B
    const size_t Z_BYTES    = 256;

    int* grid = (int*)ws;
    int* nbl  = (int*)(ws + GRID_BYTES);
    unsigned short* wpk1 = (unsigned short*)(ws + GRID_BYTES + NB_BYTES);
    unsigned short* wpk2 = (unsigned short*)(ws + GRID_BYTES + NB_BYTES + WPK_BYTES);
    unsigned short* wpk3 = (unsigned short*)(ws + GRID_BYTES + NB_BYTES + 2 * WPK_BYTES);
    unsigned short* zrow = (unsigned short*)(ws + GRID_BYTES + NB_BYTES + 3 * WPK_BYTES);
    unsigned short* fpk_a = (unsigned short*)(ws + GRID_BYTES + NB_BYTES + 3 * WPK_BYTES + Z_BYTES); // 64 MB
    unsigned short* fpk_b = (unsigned short*)d_out;  // 64 MB, overwritten by final f32 out
    float* out = (float*)d_out;

    hipMemsetAsync(grid, 0xFF, GRID_BYTES, stream);
    hipMemsetAsync(zrow, 0, Z_BYTES, stream);
    scatter_kernel<<<(M + 255) / 256, 256, 0, stream>>>(coordinates, grid);
    build_nb_kernel<<<(MP + 255) / 256, 256, 0, stream>>>(coordinates, grid, nbl);

    const int PW = NK * 2 * 64;
    prep_w_kernel<<<(PW + 255) / 256, 256, 0, stream>>>(W1, wpk1);
    prep_w_kernel<<<(PW + 255) / 256, 256, 0, stream>>>(W2, wpk2);
    prep_w_kernel<<<(PW + 255) / 256, 256, 0, stream>>>(W3, wpk3);

    split_in_kernel<<<(M * 8 + 255) / 256, 256, 0, stream>>>(features, fpk_a);

    const int nwave = MP / 64;             // 7813
    const int nblk  = (nwave + 3) / 4;     // 1954
    conv_mfma<true,  false><<<nblk, 256, 0, stream>>>(fpk_a, nbl, wpk1, zrow, fpk_b, nullptr);
    conv_mfma<true,  false><<<nblk, 256, 0, stream>>>(fpk_b, nbl, wpk2, zrow, fpk_a, nullptr);
    conv_mfma<false, true ><<<nblk, 256, 0, stream>>>(fpk_a, nbl, wpk3, zrow, nullptr, out);
}